// Round 4
// baseline (276.965 us; speedup 1.0000x reference)
//
#include <hip/hip_runtime.h>
#include <math.h>

#define BB 32
#define PP 32768
#define OO 50
#define NC 21
#define NBIN 65536
#define MPT 4            // priors per thread in match_kernel

typedef unsigned long long u64;
typedef unsigned int u32;
typedef unsigned char u8;

// workspace layout (all offsets 128B-aligned)
static constexpr size_t OFF_KEYS  = 0;                           // u64[BB*OO]
static constexpr size_t OFF_BTOV  = 16384;                       // float[BB*PP]
static constexpr size_t OFF_BTIDX = OFF_BTOV  + 4ull*BB*PP;      // u8[BB*PP]
static constexpr size_t OFF_CEM   = OFF_BTIDX + 1ull*BB*PP;      // float[BB*PP]
static constexpr size_t OFF_NPOS  = OFF_CEM   + 4ull*BB*PP;      // int[BB]
static constexpr size_t OFF_SELT  = OFF_NPOS  + 128;             // u32[BB] threshold top16 bin
static constexpr size_t OFF_SELK  = OFF_SELT  + 128;             // int[BB] residual k within bin
static constexpr size_t OFF_DACC  = OFF_SELK  + 128;             // double[3*BB]: lossl, posce, topk
static constexpr size_t OFF_HIST  = OFF_DACC  + 8ull*3*BB + 64;  // u32[BB*NBIN]
static constexpr size_t OFF_HIST2 = OFF_HIST  + 4ull*BB*NBIN;    // u32[BB*NBIN]

__global__ void init_kernel(u64* __restrict__ keys, int* __restrict__ npos,
                            double* __restrict__ dacc) {
    int i = blockIdx.x * 256 + threadIdx.x;
    if (i < BB * OO) keys[i] = 0ull;
    if (i < BB) npos[i] = 0;
    if (i < 3 * BB) dacc[i] = 0.0;
}

static __device__ __forceinline__ float fast_div(float a, float b) {
    // v_rcp_f32 approx (~1 ulp). IoU feeds threshold/argmax decisions whose
    // rare ULP-level flips perturb the final loss by << the 0.35 abs threshold.
    return a * __builtin_amdgcn_rcpf(b);
}

// Per (b, 4 priors): IoU against all 50 truths. Per-prior best truth is
// thread-local (strict > keeps first max over o). Per-truth best prior:
// float-only 64-lane butterfly max, then 4 ordered ballots pick the smallest
// (slot, lane) == smallest p (numpy argmax first-occurrence), packed into a
// u64 key (value_bits<<32 | ~p) merged across waves/blocks via atomicMax.
__global__ __launch_bounds__(256) void match_kernel(
    const float* __restrict__ priors, const float* __restrict__ targets,
    float* __restrict__ btov, u8* __restrict__ btidx, u64* __restrict__ keys)
{
#pragma clang fp contract(off)
    const int b = blockIdx.y;
    const int tid = threadIdx.x;
    const int lane = tid & 63, wid = tid >> 6;
    const int wbase = blockIdx.x * (256 * MPT) + wid * (64 * MPT);  // wave covers 256 priors

    __shared__ float tr[OO * 5];
    __shared__ u64 wkeys[4][OO];
    if (tid < OO * 5) tr[tid] = targets[(size_t)b * OO * 5 + tid];
    __syncthreads();

    float px1[MPT], py1[MPT], px2[MPT], py2[MPT], area_p[MPT];
#pragma unroll
    for (int s = 0; s < MPT; ++s) {
        int p = wbase + s * 64 + lane;
        float4 pr = *(const float4*)(priors + (size_t)p * 4);
        px1[s] = pr.x - pr.z * 0.5f; py1[s] = pr.y - pr.w * 0.5f;
        px2[s] = pr.x + pr.z * 0.5f; py2[s] = pr.y + pr.w * 0.5f;
        area_p[s] = (px2[s] - px1[s]) * (py2[s] - py1[s]);
    }

    float bestv[MPT]; int besto[MPT];
#pragma unroll
    for (int s = 0; s < MPT; ++s) { bestv[s] = -1.0f; besto[s] = 0; }

    for (int o = 0; o < OO; ++o) {
        float tx1 = tr[o*5+0], ty1 = tr[o*5+1], tx2 = tr[o*5+2], ty2 = tr[o*5+3];
        float area_t = (tx2 - tx1) * (ty2 - ty1);
        float iou[MPT];
#pragma unroll
        for (int s = 0; s < MPT; ++s) {
            float ix1 = fmaxf(tx1, px1[s]), iy1 = fmaxf(ty1, py1[s]);
            float ix2 = fminf(tx2, px2[s]), iy2 = fminf(ty2, py2[s]);
            float dx = fmaxf(ix2 - ix1, 0.0f), dy = fmaxf(iy2 - iy1, 0.0f);
            float inter = dx * dy;
            iou[s] = fast_div(inter, (area_t + area_p[s]) - inter);
            if (iou[s] > bestv[s]) { bestv[s] = iou[s]; besto[s] = o; }
        }
        // wave max of all 4 slots (float-only butterfly)
        float mv = fmaxf(fmaxf(iou[0], iou[1]), fmaxf(iou[2], iou[3]));
        for (int m = 1; m < 64; m <<= 1)
            mv = fmaxf(mv, __shfl_xor(mv, m, 64));
        // winner = smallest slot, then smallest lane  => smallest p
        u64 b0 = __ballot(iou[0] == mv);
        u64 b1 = __ballot(iou[1] == mv);
        u64 b2 = __ballot(iou[2] == mv);
        u64 b3 = __ballot(iou[3] == mv);
        if (lane == 0) {
            int s, l;
            if      (b0) { s = 0; l = __ffsll(b0) - 1; }
            else if (b1) { s = 1; l = __ffsll(b1) - 1; }
            else if (b2) { s = 2; l = __ffsll(b2) - 1; }
            else if (b3) { s = 3; l = __ffsll(b3) - 1; }
            else         { s = 0; l = 0; }
            u32 wp = (u32)(wbase + s * 64 + l);
            wkeys[wid][o] = ((u64)__float_as_uint(mv) << 32) | (u64)(0xFFFFFFFFu - wp);
        }
    }
#pragma unroll
    for (int s = 0; s < MPT; ++s) {
        int p = wbase + s * 64 + lane;
        btov[(size_t)b * PP + p] = bestv[s];
        btidx[(size_t)b * PP + p] = (u8)besto[s];
    }
    __syncthreads();
    if (tid < OO) {
        u64 k0 = wkeys[0][tid];
        for (int w = 1; w < 4; ++w) { u64 kw = wkeys[w][tid]; if (kw > k0) k0 = kw; }
        atomicMax(&keys[b * OO + tid], k0);
    }
}

// Parallel last-wins scatter: truth o writes only if no later truth o2>o picked
// the same prior (matches numpy fancy-assignment last-wins). One wave per b.
__global__ void override_kernel(const u64* __restrict__ keys,
                                float* __restrict__ btov, u8* __restrict__ btidx) {
    const int b = blockIdx.x;
    const int o = threadIdx.x;   // 64 threads = 1 wave
    u32 p = 0xFFFFFFFFu;
    if (o < OO) p = 0xFFFFFFFFu - (u32)(keys[b * OO + o] & 0xFFFFFFFFull);
    bool win = (o < OO);
    for (int o2 = 1; o2 < OO; ++o2) {
        u32 p2 = __shfl(p, o2, 64);
        if (o < o2 && p2 == p) win = false;
    }
    if (win) {
        btov[(size_t)b * PP + p] = 2.0f;
        btidx[(size_t)b * PP + p] = (u8)o;
    }
}

static __device__ __forceinline__ u32 top16bits(float v) {
    u32 u = __float_as_uint(v);
    return (v > 0.0f) ? u : 0u;
}

__global__ __launch_bounds__(256) void score_kernel(
    const float* __restrict__ loc, const float* __restrict__ conf,
    const float* __restrict__ priors, const float* __restrict__ targets,
    const float* __restrict__ btov, const u8* __restrict__ btidx,
    float* __restrict__ cemine, int* __restrict__ npos, double* __restrict__ dacc,
    u32* __restrict__ hist)
{
    const int b = blockIdx.y;
    const int p0 = blockIdx.x * 256;
    const int p = p0 + threadIdx.x;
    const int tid = threadIdx.x;
    __shared__ float tr[OO * 5];
    __shared__ float scf[256 * NC];        // conf slab; reused for reductions
    if (tid < OO * 5) tr[tid] = targets[(size_t)b * OO * 5 + tid];

    // coalesced conf load: 21 fully-coalesced dword rounds -> LDS row-major
    {
        const float* cb = conf + ((size_t)b * PP + p0) * NC;
#pragma unroll
        for (int j = 0; j < NC; ++j) scf[j * 256 + tid] = cb[j * 256 + tid];
    }
    __syncthreads();

    float ov = btov[(size_t)b * PP + p];
    int o = btidx[(size_t)b * PP + p];
    int conft = 0;
    if (ov >= 0.5f) conft = (int)(tr[o*5+4] + 1.0f);
    bool pos = conft > 0;

    const float* row = scf + tid * NC;     // stride 21 (odd) -> 2-way bank alias, free
    float m = -1e30f;
#pragma unroll
    for (int c = 0; c < NC; ++c) m = fmaxf(m, row[c]);
    float s = 0.0f, tl = 0.0f;
#pragma unroll
    for (int c = 0; c < NC; ++c) { s += expf(row[c] - m); if (c == conft) tl = row[c]; }
    float ce = (m + logf(s)) - tl;

    float cev = pos ? 0.0f : ce;
    cemine[(size_t)b * PP + p] = cev;
    atomicAdd(&hist[(size_t)b * NBIN + (top16bits(cev) >> 16)], 1u);

    double l_l = 0.0, pce = 0.0; int np_ = 0;
    if (pos) {
        np_ = 1; pce = (double)ce;
        float mx1 = tr[o*5+0], my1 = tr[o*5+1], mx2 = tr[o*5+2], my2 = tr[o*5+3];
        float4 pr = *(const float4*)(priors + (size_t)p * 4);
        float lt0 = ((mx1 + mx2) * 0.5f - pr.x) / (0.1f * pr.z);
        float lt1 = ((my1 + my2) * 0.5f - pr.y) / (0.1f * pr.w);
        float lt2 = logf((mx2 - mx1) / pr.z) / 0.2f;
        float lt3 = logf((my2 - my1) / pr.w) / 0.2f;
        const float* lp = loc + ((size_t)b * PP + p) * 4;
        float lt[4] = {lt0, lt1, lt2, lt3};
#pragma unroll
        for (int i2 = 0; i2 < 4; ++i2) {
            float d = lp[i2] - lt[i2];
            float ad = fabsf(d);
            l_l += (double)(ad < 1.0f ? 0.5f * d * d : ad - 0.5f);
        }
    }

    __syncthreads();                       // done reading scf; reuse for reductions
    double* rl = (double*)scf;             // 256 doubles
    double* rc = rl + 256;                 // 256 doubles
    int*    rn = (int*)(rc + 256);         // 256 ints
    rl[tid] = l_l; rc[tid] = pce; rn[tid] = np_;
    __syncthreads();
    for (int s2 = 128; s2 > 0; s2 >>= 1) {
        if (tid < s2) { rl[tid] += rl[tid+s2]; rc[tid] += rc[tid+s2]; rn[tid] += rn[tid+s2]; }
        __syncthreads();
    }
    if (tid == 0) {
        atomicAdd(&dacc[b], rl[0]);
        atomicAdd(&dacc[BB + b], rc[0]);
        atomicAdd(&npos[b], rn[0]);
    }
}

// Find threshold bin T16 and residual count k2. Wave-parallel coalesced
// per-chunk totals -> block suffix scan (256 chunks) -> in-chunk suffix scan.
__global__ __launch_bounds__(256) void select16_kernel(
    const u32* __restrict__ hist, const int* __restrict__ npos,
    u32* __restrict__ selT, int* __restrict__ selK)
{
    const int b = blockIdx.x, tid = threadIdx.x;
    const int lane = tid & 63, wid = tid >> 6;
    int k = npos[b] * 3; if (k > PP - 1) k = PP - 1;
    if (k <= 0) { if (tid == 0) { selT[b] = 0x10000u; selK[b] = 0; } return; }
    const u32* h = hist + (size_t)b * NBIN;

    __shared__ u32 ct[256];
    __shared__ u32 sT;
    // phase A: per-chunk counts (wave-parallel, coalesced reads)
    for (int c = wid; c < 256; c += 4) {
        u32 cnt = 0;
#pragma unroll
        for (int q = 0; q < 4; ++q) cnt += h[c * 256 + q * 64 + lane];
        for (int m = 1; m < 64; m <<= 1) cnt += __shfl_xor(cnt, m, 64);
        if (lane == 0) ct[c] = cnt;
    }
    if (tid == 0) sT = 0;
    __syncthreads();
    // phase B: suffix scan over chunk totals
    for (int off = 1; off < 256; off <<= 1) {
        u32 add = (tid + off < 256) ? ct[tid + off] : 0;
        __syncthreads();
        ct[tid] += add;
        __syncthreads();
    }
    if (ct[tid] >= (u32)k) atomicMax(&sT, (u32)tid);   // flags form a prefix
    __syncthreads();
    const int cT = (int)sT;
    const u32 aboveChunk = (cT < 255) ? ct[cT + 1] : 0;
    __syncthreads();
    // phase C: within chunk cT
    u32 v = h[cT * 256 + tid];
    ct[tid] = v;
    if (tid == 0) sT = 0;
    __syncthreads();
    for (int off = 1; off < 256; off <<= 1) {
        u32 add = (tid + off < 256) ? ct[tid + off] : 0;
        __syncthreads();
        ct[tid] += add;
        __syncthreads();
    }
    if (aboveChunk + ct[tid] >= (u32)k) atomicMax(&sT, (u32)tid);
    __syncthreads();
    const int T = (int)sT;
    if (tid == T) {
        u32 aboveBin = aboveChunk + ((T < 255) ? ct[T + 1] : 0);
        selT[b] = (u32)(cT * 256 + T);
        selK[b] = k - (int)aboveBin;
    }
}

// Pass 2: sum above threshold bin (double atomics) + low-16 histogram inside it.
__global__ __launch_bounds__(256) void scan2_kernel(
    const float* __restrict__ cemine, const u32* __restrict__ selT,
    u32* __restrict__ hist2, double* __restrict__ dacc)
{
    const int b = blockIdx.y, tid = threadIdx.x;
    const u32 T16 = selT[b];
    const float4* v4 = (const float4*)(cemine + (size_t)b * PP);
    u32* h2 = hist2 + (size_t)b * NBIN;
    float4 f = v4[blockIdx.x * 256 + tid];
    double acc = 0.0;
    float vv[4] = {f.x, f.y, f.z, f.w};
#pragma unroll
    for (int c = 0; c < 4; ++c) {
        u32 u = top16bits(vv[c]);
        u32 hi = u >> 16;
        if (hi > T16) acc += (double)vv[c];
        else if (hi == T16) atomicAdd(&h2[u & 0xFFFFu], 1u);
    }
    __shared__ double red[256];
    red[tid] = acc;
    __syncthreads();
    for (int s2 = 128; s2 > 0; s2 >>= 1) {
        if (tid < s2) red[tid] += red[tid + s2];
        __syncthreads();
    }
    if (tid == 0 && red[0] != 0.0) atomicAdd(&dacc[2 * BB + b], red[0]);
}

// Final: exact within-bin top-k2 sum; values reconstructed as (T16<<16)|low16.
// Same wave-parallel structure as select16 but carrying count*value sums.
__global__ __launch_bounds__(256) void selfinal_kernel(
    const u32* __restrict__ hist2, const u32* __restrict__ selT,
    const int* __restrict__ selK, double* __restrict__ dacc)
{
    const int b = blockIdx.x, tid = threadIdx.x;
    const int lane = tid & 63, wid = tid >> 6;
    const int k2 = selK[b];
    if (k2 <= 0) return;
    const u32 T16 = selT[b];
    const u32* h2 = hist2 + (size_t)b * NBIN;
    __shared__ u32 ct[256];
    __shared__ double sm[256];
    __shared__ u32 sT;
    for (int c = wid; c < 256; c += 4) {
        u32 cnt = 0; double s = 0.0;
#pragma unroll
        for (int q = 0; q < 4; ++q) {
            int bin = c * 256 + q * 64 + lane;
            u32 v = h2[bin];
            cnt += v;
            s += (double)v * (double)__uint_as_float((T16 << 16) | (u32)bin);
        }
        for (int m = 1; m < 64; m <<= 1) {
            cnt += __shfl_xor(cnt, m, 64);
            s   += __shfl_xor(s, m, 64);
        }
        if (lane == 0) { ct[c] = cnt; sm[c] = s; }
    }
    if (tid == 0) sT = 0;
    __syncthreads();
    for (int off = 1; off < 256; off <<= 1) {
        u32 addc = (tid + off < 256) ? ct[tid + off] : 0;
        double adds = (tid + off < 256) ? sm[tid + off] : 0.0;
        __syncthreads();
        ct[tid] += addc; sm[tid] += adds;
        __syncthreads();
    }
    if (ct[tid] >= (u32)k2) atomicMax(&sT, (u32)tid);
    __syncthreads();
    const int cT = (int)sT;
    const u32 aboveC = (cT < 255) ? ct[cT + 1] : 0;
    const double aboveS = (cT < 255) ? sm[cT + 1] : 0.0;
    __syncthreads();
    // within chunk cT
    u32 v = h2[cT * 256 + tid];
    double val = (double)__uint_as_float((T16 << 16) | (u32)(cT * 256 + tid));
    ct[tid] = v; sm[tid] = (double)v * val;
    if (tid == 0) sT = 0;
    __syncthreads();
    for (int off = 1; off < 256; off <<= 1) {
        u32 addc = (tid + off < 256) ? ct[tid + off] : 0;
        double adds = (tid + off < 256) ? sm[tid + off] : 0.0;
        __syncthreads();
        ct[tid] += addc; sm[tid] += adds;
        __syncthreads();
    }
    if (aboveC + ct[tid] >= (u32)k2) atomicMax(&sT, (u32)tid);
    __syncthreads();
    const int T2 = (int)sT;
    if (tid == T2) {
        u32 aboveBin = aboveC + ((T2 < 255) ? ct[T2 + 1] : 0);
        double sAbove = aboveS + ((T2 < 255) ? sm[T2 + 1] : 0.0);
        int take = k2 - (int)aboveBin;
        dacc[2 * BB + b] += sAbove + (double)take * val;
    }
}

__global__ void finalize_kernel(const int* __restrict__ npos,
                                const double* __restrict__ dacc, float* __restrict__ out) {
    if (threadIdx.x == 0 && blockIdx.x == 0) {
        double N = 0.0, ll = 0.0, lc = 0.0;
        for (int b = 0; b < BB; ++b) {
            N += (double)npos[b];
            ll += dacc[b];
            lc += dacc[BB + b] + dacc[2 * BB + b];
        }
        out[0] = (float)(ll / N);
        out[1] = (float)(lc / N);
    }
}

extern "C" void kernel_launch(void* const* d_in, const int* in_sizes, int n_in,
                              void* d_out, int out_size, void* d_ws, size_t ws_size,
                              hipStream_t stream) {
    const float* loc     = (const float*)d_in[0];
    const float* conf    = (const float*)d_in[1];
    const float* priors  = (const float*)d_in[2];
    const float* targets = (const float*)d_in[3];
    char* ws = (char*)d_ws;
    u64*    keys  = (u64*)   (ws + OFF_KEYS);
    float*  btov  = (float*) (ws + OFF_BTOV);
    u8*     btidx = (u8*)    (ws + OFF_BTIDX);
    float*  cem   = (float*) (ws + OFF_CEM);
    int*    npos  = (int*)   (ws + OFF_NPOS);
    u32*    selT  = (u32*)   (ws + OFF_SELT);
    int*    selK  = (int*)   (ws + OFF_SELK);
    double* dacc  = (double*)(ws + OFF_DACC);
    u32*    hist  = (u32*)   (ws + OFF_HIST);
    u32*    hist2 = (u32*)   (ws + OFF_HIST2);
    float*  out   = (float*)d_out;

    hipMemsetAsync(hist, 0, 4ull * BB * NBIN * 2, stream);  // hist + hist2 contiguous
    init_kernel<<<7, 256, 0, stream>>>(keys, npos, dacc);
    match_kernel<<<dim3(PP / (256 * MPT), BB), 256, 0, stream>>>(priors, targets, btov, btidx, keys);
    override_kernel<<<BB, 64, 0, stream>>>(keys, btov, btidx);
    score_kernel<<<dim3(PP / 256, BB), 256, 0, stream>>>(loc, conf, priors, targets, btov, btidx, cem, npos, dacc, hist);
    select16_kernel<<<BB, 256, 0, stream>>>(hist, npos, selT, selK);
    scan2_kernel<<<dim3(32, BB), 256, 0, stream>>>(cem, selT, hist2, dacc);
    selfinal_kernel<<<BB, 256, 0, stream>>>(hist2, selT, selK, dacc);
    finalize_kernel<<<1, 64, 0, stream>>>(npos, dacc, out);
}

// Round 5
// 210.029 us; speedup vs baseline: 1.3187x; 1.3187x over previous
//
#include <hip/hip_runtime.h>
#include <math.h>

#define BB 32
#define PP 32768
#define OO 50
#define NC 21
#define NBIN 65536
#define MPT 4            // priors per thread in match_kernel

// LDS histogram window: float exponents [104,136) -> top16 bins [13312,17408)
#define WBINLO (104 << 7)
#define WBINS  4096

typedef unsigned long long u64;
typedef unsigned int u32;
typedef unsigned char u8;

// workspace layout: zero-init block first (one memset), then scratch
static constexpr size_t OFF_HIST  = 0;                            // u32[BB*NBIN]  8 MB
static constexpr size_t OFF_HIST2 = OFF_HIST  + 4ull*BB*NBIN;     // u32[BB*NBIN]  8 MB
static constexpr size_t OFF_KEYS  = OFF_HIST2 + 4ull*BB*NBIN;     // u64[BB*OO]
static constexpr size_t OFF_NPOS  = OFF_KEYS  + 8ull*BB*OO;       // int[BB]
static constexpr size_t OFF_DACC  = OFF_NPOS  + 128;              // double[3*BB]
static constexpr size_t ZERO_BYTES = OFF_DACC + 8ull*3*BB;        // memset range
static constexpr size_t OFF_BTOV  = (ZERO_BYTES + 127) & ~127ull; // float[BB*PP]
static constexpr size_t OFF_BTIDX = OFF_BTOV  + 4ull*BB*PP;       // u8[BB*PP]
static constexpr size_t OFF_CEM   = OFF_BTIDX + 1ull*BB*PP;       // float[BB*PP]
static constexpr size_t OFF_SELT  = OFF_CEM   + 4ull*BB*PP;       // u32[BB]
static constexpr size_t OFF_SELK  = OFF_SELT  + 128;              // int[BB]

static __device__ __forceinline__ float fast_div(float a, float b) {
    // v_rcp_f32 approx (~1 ulp). IoU feeds threshold/argmax decisions whose
    // rare ULP-level flips perturb the final loss by << the 0.35 abs threshold.
    return a * __builtin_amdgcn_rcpf(b);
}

// Per (b, 4 priors): IoU against all 50 truths. Per-prior best truth is
// thread-local (strict > keeps first max over o). Per-truth best prior:
// float-only 64-lane butterfly max, then 4 ordered ballots pick the smallest
// (slot, lane) == smallest p (numpy argmax first-occurrence), packed into a
// u64 key (value_bits<<32 | ~p) merged across waves/blocks via atomicMax.
__global__ __launch_bounds__(256) void match_kernel(
    const float* __restrict__ priors, const float* __restrict__ targets,
    float* __restrict__ btov, u8* __restrict__ btidx, u64* __restrict__ keys)
{
#pragma clang fp contract(off)
    const int b = blockIdx.y;
    const int tid = threadIdx.x;
    const int lane = tid & 63, wid = tid >> 6;
    const int wbase = blockIdx.x * (256 * MPT) + wid * (64 * MPT);  // wave covers 256 priors

    __shared__ float tr[OO * 5];
    __shared__ u64 wkeys[4][OO];
    if (tid < OO * 5) tr[tid] = targets[(size_t)b * OO * 5 + tid];
    __syncthreads();

    float px1[MPT], py1[MPT], px2[MPT], py2[MPT], area_p[MPT];
#pragma unroll
    for (int s = 0; s < MPT; ++s) {
        int p = wbase + s * 64 + lane;
        float4 pr = *(const float4*)(priors + (size_t)p * 4);
        px1[s] = pr.x - pr.z * 0.5f; py1[s] = pr.y - pr.w * 0.5f;
        px2[s] = pr.x + pr.z * 0.5f; py2[s] = pr.y + pr.w * 0.5f;
        area_p[s] = (px2[s] - px1[s]) * (py2[s] - py1[s]);
    }

    float bestv[MPT]; int besto[MPT];
#pragma unroll
    for (int s = 0; s < MPT; ++s) { bestv[s] = -1.0f; besto[s] = 0; }

    for (int o = 0; o < OO; ++o) {
        float tx1 = tr[o*5+0], ty1 = tr[o*5+1], tx2 = tr[o*5+2], ty2 = tr[o*5+3];
        float area_t = (tx2 - tx1) * (ty2 - ty1);
        float iou[MPT];
#pragma unroll
        for (int s = 0; s < MPT; ++s) {
            float ix1 = fmaxf(tx1, px1[s]), iy1 = fmaxf(ty1, py1[s]);
            float ix2 = fminf(tx2, px2[s]), iy2 = fminf(ty2, py2[s]);
            float dx = fmaxf(ix2 - ix1, 0.0f), dy = fmaxf(iy2 - iy1, 0.0f);
            float inter = dx * dy;
            iou[s] = fast_div(inter, (area_t + area_p[s]) - inter);
            if (iou[s] > bestv[s]) { bestv[s] = iou[s]; besto[s] = o; }
        }
        // wave max of all 4 slots (float-only butterfly)
        float mv = fmaxf(fmaxf(iou[0], iou[1]), fmaxf(iou[2], iou[3]));
        for (int m = 1; m < 64; m <<= 1)
            mv = fmaxf(mv, __shfl_xor(mv, m, 64));
        // winner = smallest slot, then smallest lane  => smallest p
        u64 b0 = __ballot(iou[0] == mv);
        u64 b1 = __ballot(iou[1] == mv);
        u64 b2 = __ballot(iou[2] == mv);
        u64 b3 = __ballot(iou[3] == mv);
        if (lane == 0) {
            int s, l;
            if      (b0) { s = 0; l = __ffsll(b0) - 1; }
            else if (b1) { s = 1; l = __ffsll(b1) - 1; }
            else if (b2) { s = 2; l = __ffsll(b2) - 1; }
            else if (b3) { s = 3; l = __ffsll(b3) - 1; }
            else         { s = 0; l = 0; }
            u32 wp = (u32)(wbase + s * 64 + l);
            wkeys[wid][o] = ((u64)__float_as_uint(mv) << 32) | (u64)(0xFFFFFFFFu - wp);
        }
    }
#pragma unroll
    for (int s = 0; s < MPT; ++s) {
        int p = wbase + s * 64 + lane;
        btov[(size_t)b * PP + p] = bestv[s];
        btidx[(size_t)b * PP + p] = (u8)besto[s];
    }
    __syncthreads();
    if (tid < OO) {
        u64 k0 = wkeys[0][tid];
        for (int w = 1; w < 4; ++w) { u64 kw = wkeys[w][tid]; if (kw > k0) k0 = kw; }
        atomicMax(&keys[b * OO + tid], k0);
    }
}

// Parallel last-wins scatter: truth o writes only if no later truth o2>o picked
// the same prior (matches numpy fancy-assignment last-wins). One wave per b.
__global__ void override_kernel(const u64* __restrict__ keys,
                                float* __restrict__ btov, u8* __restrict__ btidx) {
    const int b = blockIdx.x;
    const int o = threadIdx.x;   // 64 threads = 1 wave
    u32 p = 0xFFFFFFFFu;
    if (o < OO) p = 0xFFFFFFFFu - (u32)(keys[b * OO + o] & 0xFFFFFFFFull);
    bool win = (o < OO);
    for (int o2 = 1; o2 < OO; ++o2) {
        u32 p2 = __shfl(p, o2, 64);
        if (o < o2 && p2 == p) win = false;
    }
    if (win) {
        btov[(size_t)b * PP + p] = 2.0f;
        btidx[(size_t)b * PP + p] = (u8)o;
    }
}

static __device__ __forceinline__ u32 top16bits(float v) {
    u32 u = __float_as_uint(v);
    return (v > 0.0f) ? u : 0u;
}

__global__ __launch_bounds__(256) void score_kernel(
    const float* __restrict__ loc, const float* __restrict__ conf,
    const float* __restrict__ priors, const float* __restrict__ targets,
    const float* __restrict__ btov, const u8* __restrict__ btidx,
    float* __restrict__ cemine, int* __restrict__ npos, double* __restrict__ dacc,
    u32* __restrict__ hist)
{
    const int b = blockIdx.y;
    const int p0 = blockIdx.x * 256;
    const int p = p0 + threadIdx.x;
    const int tid = threadIdx.x;
    __shared__ float tr[OO * 5];
    __shared__ float scf[256 * NC];        // conf slab; reused for hist + reductions
    if (tid < OO * 5) tr[tid] = targets[(size_t)b * OO * 5 + tid];

    // coalesced conf load: 21 fully-coalesced dword rounds -> LDS row-major
    {
        const float* cb = conf + ((size_t)b * PP + p0) * NC;
#pragma unroll
        for (int j = 0; j < NC; ++j) scf[j * 256 + tid] = cb[j * 256 + tid];
    }
    __syncthreads();

    float ov = btov[(size_t)b * PP + p];
    int o = btidx[(size_t)b * PP + p];
    int conft = 0;
    if (ov >= 0.5f) conft = (int)(tr[o*5+4] + 1.0f);
    bool pos = conft > 0;

    const float* row = scf + tid * NC;     // stride 21 (odd) -> 2-way bank alias, free
    float m = -1e30f;
#pragma unroll
    for (int c = 0; c < NC; ++c) m = fmaxf(m, row[c]);
    float s = 0.0f, tl = 0.0f;
#pragma unroll
    for (int c = 0; c < NC; ++c) { s += expf(row[c] - m); if (c == conft) tl = row[c]; }
    float ce = (m + logf(s)) - tl;

    float cev = pos ? 0.0f : ce;
    cemine[(size_t)b * PP + p] = cev;

    double l_l = 0.0, pce = 0.0; int np_ = 0;
    if (pos) {
        np_ = 1; pce = (double)ce;
        float mx1 = tr[o*5+0], my1 = tr[o*5+1], mx2 = tr[o*5+2], my2 = tr[o*5+3];
        float4 pr = *(const float4*)(priors + (size_t)p * 4);
        float lt0 = ((mx1 + mx2) * 0.5f - pr.x) / (0.1f * pr.z);
        float lt1 = ((my1 + my2) * 0.5f - pr.y) / (0.1f * pr.w);
        float lt2 = logf((mx2 - mx1) / pr.z) / 0.2f;
        float lt3 = logf((my2 - my1) / pr.w) / 0.2f;
        const float* lp = loc + ((size_t)b * PP + p) * 4;
        float lt[4] = {lt0, lt1, lt2, lt3};
#pragma unroll
        for (int i2 = 0; i2 < 4; ++i2) {
            float d = lp[i2] - lt[i2];
            float ad = fabsf(d);
            l_l += (double)(ad < 1.0f ? 0.5f * d * d : ad - 0.5f);
        }
    }

    __syncthreads();                       // done reading scf; reuse the LDS
    u32*    hh = (u32*)scf;                // [WBINS] window histogram (16 KB)
    double* rl = (double*)(scf + WBINS);   // 256 doubles
    double* rc = rl + 256;                 // 256 doubles
    int*    rn = (int*)(rc + 256);         // 256 ints
#pragma unroll
    for (int j = 0; j < WBINS / 256; ++j) hh[j * 256 + tid] = 0;
    rl[tid] = l_l; rc[tid] = pce; rn[tid] = np_;
    __syncthreads();

    // LDS pre-aggregated histogram (exact): window bins in LDS, zeros via
    // ballot+popcount (1 atomic/wave), out-of-window direct (measure-zero).
    u32 t16 = top16bits(cev) >> 16;
    if (t16 != 0) {
        int widx = (int)t16 - WBINLO;
        if ((unsigned)widx < WBINS) atomicAdd(&hh[widx], 1u);
        else atomicAdd(&hist[(size_t)b * NBIN + t16], 1u);
    }
    u64 zb = __ballot(t16 == 0);
    if ((tid & 63) == 0 && zb) atomicAdd(&hist[(size_t)b * NBIN], (u32)__popcll(zb));
    __syncthreads();

    // flush nonzero window bins (~hundreds) + block reduction
#pragma unroll
    for (int j = 0; j < WBINS / 256; ++j) {
        u32 c = hh[j * 256 + tid];
        if (c) atomicAdd(&hist[(size_t)b * NBIN + WBINLO + j * 256 + tid], c);
    }
    for (int s2 = 128; s2 > 0; s2 >>= 1) {
        if (tid < s2) { rl[tid] += rl[tid+s2]; rc[tid] += rc[tid+s2]; rn[tid] += rn[tid+s2]; }
        __syncthreads();
    }
    if (tid == 0) {
        atomicAdd(&dacc[b], rl[0]);
        atomicAdd(&dacc[BB + b], rc[0]);
        atomicAdd(&npos[b], rn[0]);
    }
}

// Find threshold bin T16 and residual count k2. Wave-parallel coalesced
// per-chunk totals -> block suffix scan (256 chunks) -> in-chunk suffix scan.
__global__ __launch_bounds__(256) void select16_kernel(
    const u32* __restrict__ hist, const int* __restrict__ npos,
    u32* __restrict__ selT, int* __restrict__ selK)
{
    const int b = blockIdx.x, tid = threadIdx.x;
    const int lane = tid & 63, wid = tid >> 6;
    int k = npos[b] * 3; if (k > PP - 1) k = PP - 1;
    if (k <= 0) { if (tid == 0) { selT[b] = 0x10000u; selK[b] = 0; } return; }
    const u32* h = hist + (size_t)b * NBIN;

    __shared__ u32 ct[256];
    __shared__ u32 sT;
    for (int c = wid; c < 256; c += 4) {
        u32 cnt = 0;
#pragma unroll
        for (int q = 0; q < 4; ++q) cnt += h[c * 256 + q * 64 + lane];
        for (int m = 1; m < 64; m <<= 1) cnt += __shfl_xor(cnt, m, 64);
        if (lane == 0) ct[c] = cnt;
    }
    if (tid == 0) sT = 0;
    __syncthreads();
    for (int off = 1; off < 256; off <<= 1) {
        u32 add = (tid + off < 256) ? ct[tid + off] : 0;
        __syncthreads();
        ct[tid] += add;
        __syncthreads();
    }
    if (ct[tid] >= (u32)k) atomicMax(&sT, (u32)tid);   // flags form a prefix
    __syncthreads();
    const int cT = (int)sT;
    const u32 aboveChunk = (cT < 255) ? ct[cT + 1] : 0;
    __syncthreads();
    u32 v = h[cT * 256 + tid];
    ct[tid] = v;
    if (tid == 0) sT = 0;
    __syncthreads();
    for (int off = 1; off < 256; off <<= 1) {
        u32 add = (tid + off < 256) ? ct[tid + off] : 0;
        __syncthreads();
        ct[tid] += add;
        __syncthreads();
    }
    if (aboveChunk + ct[tid] >= (u32)k) atomicMax(&sT, (u32)tid);
    __syncthreads();
    const int T = (int)sT;
    if (tid == T) {
        u32 aboveBin = aboveChunk + ((T < 255) ? ct[T + 1] : 0);
        selT[b] = (u32)(cT * 256 + T);
        selK[b] = k - (int)aboveBin;
    }
}

// Pass 2: sum above threshold bin (double atomics) + low-16 histogram inside it.
__global__ __launch_bounds__(256) void scan2_kernel(
    const float* __restrict__ cemine, const u32* __restrict__ selT,
    u32* __restrict__ hist2, double* __restrict__ dacc)
{
    const int b = blockIdx.y, tid = threadIdx.x;
    const u32 T16 = selT[b];
    const float4* v4 = (const float4*)(cemine + (size_t)b * PP);
    u32* h2 = hist2 + (size_t)b * NBIN;
    float4 f = v4[blockIdx.x * 256 + tid];
    double acc = 0.0;
    float vv[4] = {f.x, f.y, f.z, f.w};
#pragma unroll
    for (int c = 0; c < 4; ++c) {
        u32 u = top16bits(vv[c]);
        u32 hi = u >> 16;
        if (hi > T16) acc += (double)vv[c];
        else if (hi == T16) atomicAdd(&h2[u & 0xFFFFu], 1u);
    }
    __shared__ double red[256];
    red[tid] = acc;
    __syncthreads();
    for (int s2 = 128; s2 > 0; s2 >>= 1) {
        if (tid < s2) red[tid] += red[tid + s2];
        __syncthreads();
    }
    if (tid == 0 && red[0] != 0.0) atomicAdd(&dacc[2 * BB + b], red[0]);
}

// Final: exact within-bin top-k2 sum; values reconstructed as (T16<<16)|low16.
__global__ __launch_bounds__(256) void selfinal_kernel(
    const u32* __restrict__ hist2, const u32* __restrict__ selT,
    const int* __restrict__ selK, double* __restrict__ dacc)
{
    const int b = blockIdx.x, tid = threadIdx.x;
    const int lane = tid & 63, wid = tid >> 6;
    const int k2 = selK[b];
    if (k2 <= 0) return;
    const u32 T16 = selT[b];
    const u32* h2 = hist2 + (size_t)b * NBIN;
    __shared__ u32 ct[256];
    __shared__ double sm[256];
    __shared__ u32 sT;
    for (int c = wid; c < 256; c += 4) {
        u32 cnt = 0; double s = 0.0;
#pragma unroll
        for (int q = 0; q < 4; ++q) {
            int bin = c * 256 + q * 64 + lane;
            u32 v = h2[bin];
            cnt += v;
            s += (double)v * (double)__uint_as_float((T16 << 16) | (u32)bin);
        }
        for (int m = 1; m < 64; m <<= 1) {
            cnt += __shfl_xor(cnt, m, 64);
            s   += __shfl_xor(s, m, 64);
        }
        if (lane == 0) { ct[c] = cnt; sm[c] = s; }
    }
    if (tid == 0) sT = 0;
    __syncthreads();
    for (int off = 1; off < 256; off <<= 1) {
        u32 addc = (tid + off < 256) ? ct[tid + off] : 0;
        double adds = (tid + off < 256) ? sm[tid + off] : 0.0;
        __syncthreads();
        ct[tid] += addc; sm[tid] += adds;
        __syncthreads();
    }
    if (ct[tid] >= (u32)k2) atomicMax(&sT, (u32)tid);
    __syncthreads();
    const int cT = (int)sT;
    const u32 aboveC = (cT < 255) ? ct[cT + 1] : 0;
    const double aboveS = (cT < 255) ? sm[cT + 1] : 0.0;
    __syncthreads();
    u32 v = h2[cT * 256 + tid];
    double val = (double)__uint_as_float((T16 << 16) | (u32)(cT * 256 + tid));
    ct[tid] = v; sm[tid] = (double)v * val;
    if (tid == 0) sT = 0;
    __syncthreads();
    for (int off = 1; off < 256; off <<= 1) {
        u32 addc = (tid + off < 256) ? ct[tid + off] : 0;
        double adds = (tid + off < 256) ? sm[tid + off] : 0.0;
        __syncthreads();
        ct[tid] += addc; sm[tid] += adds;
        __syncthreads();
    }
    if (aboveC + ct[tid] >= (u32)k2) atomicMax(&sT, (u32)tid);
    __syncthreads();
    const int T2 = (int)sT;
    if (tid == T2) {
        u32 aboveBin = aboveC + ((T2 < 255) ? ct[T2 + 1] : 0);
        double sAbove = aboveS + ((T2 < 255) ? sm[T2 + 1] : 0.0);
        int take = k2 - (int)aboveBin;
        dacc[2 * BB + b] += sAbove + (double)take * val;
    }
}

__global__ void finalize_kernel(const int* __restrict__ npos,
                                const double* __restrict__ dacc, float* __restrict__ out) {
    if (threadIdx.x == 0 && blockIdx.x == 0) {
        double N = 0.0, ll = 0.0, lc = 0.0;
        for (int b = 0; b < BB; ++b) {
            N += (double)npos[b];
            ll += dacc[b];
            lc += dacc[BB + b] + dacc[2 * BB + b];
        }
        out[0] = (float)(ll / N);
        out[1] = (float)(lc / N);
    }
}

extern "C" void kernel_launch(void* const* d_in, const int* in_sizes, int n_in,
                              void* d_out, int out_size, void* d_ws, size_t ws_size,
                              hipStream_t stream) {
    const float* loc     = (const float*)d_in[0];
    const float* conf    = (const float*)d_in[1];
    const float* priors  = (const float*)d_in[2];
    const float* targets = (const float*)d_in[3];
    char* ws = (char*)d_ws;
    u32*    hist  = (u32*)   (ws + OFF_HIST);
    u32*    hist2 = (u32*)   (ws + OFF_HIST2);
    u64*    keys  = (u64*)   (ws + OFF_KEYS);
    int*    npos  = (int*)   (ws + OFF_NPOS);
    double* dacc  = (double*)(ws + OFF_DACC);
    float*  btov  = (float*) (ws + OFF_BTOV);
    u8*     btidx = (u8*)    (ws + OFF_BTIDX);
    float*  cem   = (float*) (ws + OFF_CEM);
    u32*    selT  = (u32*)   (ws + OFF_SELT);
    int*    selK  = (int*)   (ws + OFF_SELK);
    float*  out   = (float*)d_out;

    hipMemsetAsync(ws, 0, ZERO_BYTES, stream);   // hist+hist2+keys+npos+dacc
    match_kernel<<<dim3(PP / (256 * MPT), BB), 256, 0, stream>>>(priors, targets, btov, btidx, keys);
    override_kernel<<<BB, 64, 0, stream>>>(keys, btov, btidx);
    score_kernel<<<dim3(PP / 256, BB), 256, 0, stream>>>(loc, conf, priors, targets, btov, btidx, cem, npos, dacc, hist);
    select16_kernel<<<BB, 256, 0, stream>>>(hist, npos, selT, selK);
    scan2_kernel<<<dim3(32, BB), 256, 0, stream>>>(cem, selT, hist2, dacc);
    selfinal_kernel<<<BB, 256, 0, stream>>>(hist2, selT, selK, dacc);
    finalize_kernel<<<1, 64, 0, stream>>>(npos, dacc, out);
}